// Round 17
// baseline (6903.918 us; speedup 1.0000x reference)
//
#include <hip/hip_runtime.h>
#include <hip/hip_bf16.h>
#include <math.h>

#define BB 512
#define HH 512
#define TT 1024
#define BUFSZ (512*1024)

typedef __bf16 bf16;
typedef __bf16 bf16x8 __attribute__((ext_vector_type(8)));
typedef float f32x4 __attribute__((ext_vector_type(4)));
typedef unsigned long long ull;
typedef ull ull2 __attribute__((ext_vector_type(2)));

// ---------------- ws layout (bytes) ----------------
// WcT : [2048][512] bf16 @ 0      (2 MB)  folded: Whh + Wfc ⊗ Wih
// biasC: [2048] f32      @ 2 MB   (8 KB)
// hb0/1: [512][512] bf16 double-buffered h (2 x 512 KB)
// flags: [16 groups][64] int — PER-WAVE epoch slots (producer wg hs, wave w
//        -> slot hs*4+w). 256B per group.
#define WT_OFF 0
#define BC_OFF (2*1024*1024)
#define H0_OFF (BC_OFF + 8192)
#define FL_OFF (H0_OFF + 2*BUFSZ)

__global__ void prep_weights(const float* __restrict__ Whh, const float* __restrict__ Wih,
                             const float* __restrict__ bih, const float* __restrict__ bhh,
                             const float* __restrict__ Wfc, const float* __restrict__ bfc,
                             bf16* __restrict__ WcT, float* __restrict__ biasC) {
    int col = blockIdx.x;                 // 0..2047
    float wih = Wih[col];
    for (int k = threadIdx.x; k < HH; k += blockDim.x)
        WcT[col * HH + k] = (bf16)(Whh[col * HH + k] + Wfc[k] * wih);
    if (threadIdx.x == 0) biasC[col] = bih[col] + bhh[col] + bfc[0] * wih;
}

__global__ void prep_state(const float* __restrict__ h, bf16* __restrict__ h0buf,
                           int* __restrict__ flags) {
    int i = blockIdx.x * blockDim.x + threadIdx.x;
    if (i < BB * HH) h0buf[i] = (bf16)h[i];
    if (i < 16 * 64) flags[i] = 0;
}

__device__ __forceinline__ float tanh_fast(float x) {
    float ax = fabsf(x);
    float e = __expf(-2.f * ax);
    float r = (1.f - e) / (1.f + e);
    return copysignf(r, x);
}
__device__ __forceinline__ float sigmoid_fast(float x) {
    return 1.f / (1.f + __expf(-x));
}

// Persistent LSTM — r14 fabric (epoch flags + ONE coalesced data sweep via
// the MALL, sc0 sc1 — the only validated inter-wg path) with PER-WAVE flag
// publish: vmcnt is a per-wave counter, and wave w's h-stores cover exactly
// rows w*8..w*8+8, so each wave publishes its own flag right after its own
// s_waitcnt vmcnt(0) — no post-store barrier, publish ~0.3-0.5us earlier,
// flag latency decoupled from the slowest wave. Consumers poll 64 per-wave
// flags with 64 lanes (one coalesced 256B load per sweep). LDS safety
// without the removed barrier: the only cross-wave Alds reads (MFMA) are
// gated by the pre-store barrier; staging/FC/y-FC touch only the wave's
// own 8-row region. Overwrite safety (2 buffers) unchanged: flag s+1 from
// every wave of every member proves all A_{s-1} reads retired.
__global__ __launch_bounds__(256, 1) void lstm_persist(
    const bf16* __restrict__ WcT,     // [2048][512] bf16 (folded)
    const float* __restrict__ biasC,  // [2048]
    const float* __restrict__ Wih,    // [2048]
    const float* __restrict__ Wfc,    // [512]
    const float* __restrict__ bfc,    // [1]
    const float* __restrict__ c0,     // [512*512] f32
    char* __restrict__ hbase,         // 2 x 512KB buffers
    int* __restrict__ flags,          // [16*64]
    float* __restrict__ out)          // [512][1024]
{
    __shared__ __align__(16) bf16 Alds[32 * 512];  // XOR-swizzled h tile (32 KB)
    __shared__ float xls[32];                      // step-0 correction per row
    __shared__ float WfcLDS[512];
    __shared__ bf16 hrep[32][40];                  // h repack for coalesced stores

    const int tid  = threadIdx.x;
    const int wave = tid >> 6;
    const int lane = tid & 63;
    const int l15  = lane & 15;
    const int hi   = lane >> 4;
    const int xcd = blockIdx.x & 7;
    const int ii  = blockIdx.x >> 3;
    const int bt  = xcd * 2 + (ii & 1);       // 0..15
    const int hs  = ii >> 1;                  // 0..15

    WfcLDS[tid] = Wfc[tid];
    WfcLDS[tid + 256] = Wfc[tid + 256];

    bf16x8 breg[2][16];
    float biasr[2], wihr[2];
    #pragma unroll
    for (int nt = 0; nt < 2; ++nt) {
        int gcol = (nt * 2 + (l15 >> 3)) * HH + hs * 32 + wave * 8 + (l15 & 7);
        const bf16* wp = WcT + (size_t)gcol * HH + hi * 8;
        #pragma unroll
        for (int kk = 0; kk < 16; ++kk)
            breg[nt][kk] = *(const bf16x8*)(wp + kk * 32);
        biasr[nt] = biasC[gcol];
        wihr[nt]  = Wih[gcol];
    }
    const bool lo = (l15 < 8);
    float p0 = __shfl_xor(biasr[0], 8), p1 = __shfl_xor(biasr[1], 8);
    const float bI = lo ? biasr[0] : p0, bF = lo ? p0 : biasr[0];
    const float bG = lo ? biasr[1] : p1, bO = lo ? p1 : biasr[1];
    p0 = __shfl_xor(wihr[0], 8); p1 = __shfl_xor(wihr[1], 8);
    const float wI = lo ? wihr[0] : p0, wF = lo ? p0 : wihr[0];
    const float wG = lo ? wihr[1] : p1, wO = lo ? p1 : wihr[1];

    const int mymt = lo ? 0 : 1;
    const int jcol = wave * 8 + (l15 & 7);
    const int jloc = hs * 32 + jcol;
    float creg[4];
    #pragma unroll
    for (int r = 0; r < 4; ++r) {
        int brow = bt * 32 + mymt * 16 + hi * 4 + r;
        creg[r] = c0[(size_t)brow * HH + jloc];
    }
    const float bfcv = bfc[0];

    const int swz = l15 & 7;
    const int row = tid >> 3;
    const int seg = tid & 7;
    const int r7  = row & 7;

    int* myflags = flags + bt * 64;           // 64 per-wave producer slots
    int* myslot  = myflags + hs * 4 + wave;   // this wave's own slot

    const size_t grp = ((size_t)(bt * 32 + wave * 8)) * 1024 + (size_t)lane * 16;
    const size_t sto = ((size_t)(bt * 32 + row)) * 1024 + (size_t)hs * 64 + (size_t)seg * 8;
    char* aldsW = (char*)Alds + wave * 8 * 1024;

    __syncthreads();

    for (int s = 0; s <= TT; ++s) {
        if (s == TT && hs != 0) break;

        // 1. detect: 64 lanes poll the group's 64 per-wave epoch slots
        //    (one coalesced 256B load per sweep)
        {
            while (__hip_atomic_load(myflags + lane, __ATOMIC_RELAXED,
                                     __HIP_MEMORY_SCOPE_SYSTEM) < s)
                __builtin_amdgcn_s_sleep(1);
        }

        // 2. stage A_s: ONE coalesced sweep (8 x 1KB rows), swizzled LDS
        {
            const char* blo = hbase + (size_t)(s & 1) * BUFSZ + grp;
            const char* bhi = blo + 4096;
            ull2 q0, q1, q2, q3, q4, q5, q6, q7;
            asm volatile(
                "global_load_dwordx4 %0, %8, off sc0 sc1\n\t"
                "global_load_dwordx4 %1, %8, off offset:1024 sc0 sc1\n\t"
                "global_load_dwordx4 %2, %8, off offset:2048 sc0 sc1\n\t"
                "global_load_dwordx4 %3, %8, off offset:3072 sc0 sc1\n\t"
                "global_load_dwordx4 %4, %9, off sc0 sc1\n\t"
                "global_load_dwordx4 %5, %9, off offset:1024 sc0 sc1\n\t"
                "global_load_dwordx4 %6, %9, off offset:2048 sc0 sc1\n\t"
                "global_load_dwordx4 %7, %9, off offset:3072 sc0 sc1\n\t"
                "s_waitcnt vmcnt(0)"
                : "=&v"(q0), "=&v"(q1), "=&v"(q2), "=&v"(q3),
                  "=&v"(q4), "=&v"(q5), "=&v"(q6), "=&v"(q7)
                : "v"(blo), "v"(bhi) : "memory");
            __builtin_amdgcn_sched_barrier(0);
            *(ull2*)(aldsW            + ((lane ^ 0) << 4)) = q0;
            *(ull2*)(aldsW + 1 * 1024 + ((lane ^ 1) << 4)) = q1;
            *(ull2*)(aldsW + 2 * 1024 + ((lane ^ 2) << 4)) = q2;
            *(ull2*)(aldsW + 3 * 1024 + ((lane ^ 3) << 4)) = q3;
            *(ull2*)(aldsW + 4 * 1024 + ((lane ^ 4) << 4)) = q4;
            *(ull2*)(aldsW + 5 * 1024 + ((lane ^ 5) << 4)) = q5;
            *(ull2*)(aldsW + 6 * 1024 + ((lane ^ 6) << 4)) = q6;
            *(ull2*)(aldsW + 7 * 1024 + ((lane ^ 7) << 4)) = q7;
        }
        __syncthreads();   // full A_s staged

        // LDS granule map: row r, 16B-granule g at r*1024 + ((g ^ (r&7))<<4).
        if (s == 0 || s == TT) {
            float xacc = 0.f;
            const char* arow = (char*)Alds + row * 1024;
            #pragma unroll
            for (int u = 0; u < 8; ++u) {
                int cc = seg * 8 + u;
                bf16x8 v = *(const bf16x8*)(arow + (((cc ^ r7) & 63) << 4));
                const float* wv = WfcLDS + cc * 8;
                #pragma unroll
                for (int e = 0; e < 8; ++e) xacc += (float)v[e] * wv[e];
            }
            xacc += __shfl_xor(xacc, 1);
            xacc += __shfl_xor(xacc, 2);
            xacc += __shfl_xor(xacc, 4);
            xacc += bfcv;
            if (seg == 0) {
                if (s == 0) xls[row] = xacc;
                else out[((size_t)(bt * 32 + row)) * TT + (TT - 1)] = xacc;
            }
            if (s == TT) break;
        }

        // 4. MFMA (granule index (hi + 4*kk) ^ swz)
        f32x4 acc[2][2];
        #pragma unroll
        for (int i = 0; i < 2; ++i)
            #pragma unroll
            for (int j = 0; j < 2; ++j) acc[i][j] = (f32x4)0.f;

        #pragma unroll
        for (int kk = 0; kk < 16; ++kk) {
            int g = (hi + 4 * kk) ^ swz;
            bf16x8 a0 = *(const bf16x8*)((char*)Alds + l15 * 1024 + (g << 4));
            bf16x8 a1 = *(const bf16x8*)((char*)Alds + (l15 + 16) * 1024 + (g << 4));
            acc[0][0] = __builtin_amdgcn_mfma_f32_16x16x32_bf16(a0, breg[0][kk], acc[0][0], 0, 0, 0);
            acc[0][1] = __builtin_amdgcn_mfma_f32_16x16x32_bf16(a0, breg[1][kk], acc[0][1], 0, 0, 0);
            acc[1][0] = __builtin_amdgcn_mfma_f32_16x16x32_bf16(a1, breg[0][kk], acc[1][0], 0, 0, 0);
            acc[1][1] = __builtin_amdgcn_mfma_f32_16x16x32_bf16(a1, breg[1][kk], acc[1][1], 0, 0, 0);
        }

        if (s == 0) __syncthreads();

        // 5. pointwise
        #pragma unroll
        for (int r = 0; r < 4; ++r) {
            float send0 = lo ? acc[1][0][r] : acc[0][0][r];
            float send1 = lo ? acc[1][1][r] : acc[0][1][r];
            float recv0 = __shfl_xor(send0, 8);
            float recv1 = __shfl_xor(send1, 8);
            float own0  = lo ? acc[0][0][r] : acc[1][0][r];
            float own1  = lo ? acc[0][1][r] : acc[1][1][r];
            int  lrow = mymt * 16 + hi * 4 + r;
            float xc = (s == 0) ? xls[lrow] : 0.f;
            float xi = (lo ? own0 : recv0) + bI - xc * wI;
            float xf = (lo ? recv0 : own0) + bF - xc * wF;
            float xg = (lo ? own1 : recv1) + bG - xc * wG;
            float xo = (lo ? recv1 : own1) + bO - xc * wO;
            float si = sigmoid_fast(xi), sf = sigmoid_fast(xf), so = sigmoid_fast(xo);
            float tg = tanh_fast(xg);
            float cn = sf * creg[r] + si * tg;
            creg[r] = cn;
            hrep[lrow][jcol] = (bf16)(so * tanh_fast(cn));
        }
        __syncthreads();   // hrep complete (all waves); Alds MFMA reads done

        // 6. store A_{s+1} into buf[(s+1)&1]: wave w's 64 lanes cover
        //    rows w*8..w*8+8 (row = tid>>3), all 32 cols of our slice.
        {
            ull val = *(const ull*)&hrep[row][seg * 4];
            char* stp = hbase + (size_t)((s + 1) & 1) * BUFSZ + sto;
            asm volatile("global_store_dwordx2 %0, %1, off sc0 sc1"
                         :: "v"(stp), "v"(val) : "memory");
        }

        // 7. PER-WAVE publish: wave-level vmcnt(0) drains ALL this wave's
        //    stores (vmcnt is per-wave), then lane 0 publishes this wave's
        //    slot. No barrier — publish decoupled from sibling waves.
        asm volatile("s_waitcnt vmcnt(0)" ::: "memory");
        if (lane == 0)
            __hip_atomic_store(myslot, s + 1, __ATOMIC_RELAXED,
                               __HIP_MEMORY_SCOPE_SYSTEM);

        // 8. round-robin y FC (off critical path; reads THIS wave's own
        //    Alds rows only — no cross-wave hazard without barrier(3))
        if (s > 0 && (s & 15) == hs) {
            float xacc = 0.f;
            const char* arow = (char*)Alds + row * 1024;
            #pragma unroll
            for (int u = 0; u < 8; ++u) {
                int cc = seg * 8 + u;
                bf16x8 v = *(const bf16x8*)(arow + (((cc ^ r7) & 63) << 4));
                const float* wv = WfcLDS + cc * 8;
                #pragma unroll
                for (int e = 0; e < 8; ++e) xacc += (float)v[e] * wv[e];
            }
            xacc += __shfl_xor(xacc, 1);
            xacc += __shfl_xor(xacc, 2);
            xacc += __shfl_xor(xacc, 4);
            if (seg == 0)
                out[((size_t)(bt * 32 + row)) * TT + (s - 1)] = xacc + bfcv;
        }
    }
}

extern "C" void kernel_launch(void* const* d_in, const int* in_sizes, int n_in,
                              void* d_out, int out_size, void* d_ws, size_t ws_size,
                              hipStream_t stream) {
    const float* h   = (const float*)d_in[0];
    const float* c   = (const float*)d_in[1];
    const float* Wih = (const float*)d_in[2];
    const float* Whh = (const float*)d_in[3];
    const float* bih = (const float*)d_in[4];
    const float* bhh = (const float*)d_in[5];
    const float* Wfc = (const float*)d_in[6];
    const float* bfc = (const float*)d_in[7];
    float* out = (float*)d_out;

    char* ws = (char*)d_ws;
    bf16*  WcT   = (bf16*)(ws + WT_OFF);
    float* biasC = (float*)(ws + BC_OFF);
    char*  hb    = ws + H0_OFF;
    int*   flags = (int*)(ws + FL_OFF);

    prep_weights<<<2048, 256, 0, stream>>>(Whh, Wih, bih, bhh, Wfc, bfc, WcT, biasC);
    prep_state<<<1024, 256, 0, stream>>>(h, (bf16*)hb, flags);
    lstm_persist<<<256, 256, 0, stream>>>(WcT, biasC, Wih, Wfc, bfc, c, hb, flags, out);
}

// Round 18
// 3501.882 us; speedup vs baseline: 1.9715x; 1.9715x over previous
//
#include <hip/hip_runtime.h>
#include <hip/hip_bf16.h>
#include <math.h>

#define BB 512
#define HH 512
#define TT 1024
#define BUFSZ (512*1024)

typedef __bf16 bf16;
typedef __bf16 bf16x8 __attribute__((ext_vector_type(8)));
typedef float f32x4 __attribute__((ext_vector_type(4)));
typedef unsigned long long ull;
typedef ull ull2 __attribute__((ext_vector_type(2)));

// ---------------- ws layout (bytes) ----------------
// WcT : [2048][512] bf16 @ 0      (2 MB)  folded: Whh + Wfc ⊗ Wih
// biasC: [2048] f32      @ 2 MB   (8 KB)
// hb0/1: [512][512] bf16 double-buffered h (2 x 512 KB)
// flags: [16*32] int (128B-spaced groups of 16 producer epoch slots)
#define WT_OFF 0
#define BC_OFF (2*1024*1024)
#define H0_OFF (BC_OFF + 8192)
#define FL_OFF (H0_OFF + 2*BUFSZ)

__global__ void prep_weights(const float* __restrict__ Whh, const float* __restrict__ Wih,
                             const float* __restrict__ bih, const float* __restrict__ bhh,
                             const float* __restrict__ Wfc, const float* __restrict__ bfc,
                             bf16* __restrict__ WcT, float* __restrict__ biasC) {
    int col = blockIdx.x;                 // 0..2047
    float wih = Wih[col];
    for (int k = threadIdx.x; k < HH; k += blockDim.x)
        WcT[col * HH + k] = (bf16)(Whh[col * HH + k] + Wfc[k] * wih);
    if (threadIdx.x == 0) biasC[col] = bih[col] + bhh[col] + bfc[0] * wih;
}

__global__ void prep_state(const float* __restrict__ h, bf16* __restrict__ h0buf,
                           int* __restrict__ flags) {
    int i = blockIdx.x * blockDim.x + threadIdx.x;
    if (i < BB * HH) h0buf[i] = (bf16)h[i];
    if (i < 16 * 32) flags[i] = 0;
}

__device__ __forceinline__ float tanh_fast(float x) {
    float ax = fabsf(x);
    float e = __expf(-2.f * ax);
    float r = (1.f - e) / (1.f + e);
    return copysignf(r, x);
}
__device__ __forceinline__ float sigmoid_fast(float x) {
    return 1.f / (1.f + __expf(-x));
}

// Persistent LSTM — the round-14 fabric (best measured: 3.48 ms).
// Sync = per-producer epoch flags (detect, 64B/wave/sweep) + ONE coalesced
// data sweep (transfer), both via the MALL (sc0 sc1 — the only validated
// inter-wg path on this chip). No sentinels, no clear-behind, 2 buffers
// (flag s+1 from all members proves their A_{s-1} reads retired =>
// overwrite-safe). Producer publish: data stores -> __syncthreads()
// (per-thread vmcnt(0) drain) -> plain relaxed SYSTEM flag store (no RMW,
// no wbl2). The chain is latency-bound: ~3.4us/step = store-drain-publish
// + flag RT + data RT + compute; every protocol segment beyond HW latency
// has been removed (rounds 15-17 attempts to merge/split RTs all regressed).
__global__ __launch_bounds__(256, 1) void lstm_persist(
    const bf16* __restrict__ WcT,     // [2048][512] bf16 (folded)
    const float* __restrict__ biasC,  // [2048]
    const float* __restrict__ Wih,    // [2048]
    const float* __restrict__ Wfc,    // [512]
    const float* __restrict__ bfc,    // [1]
    const float* __restrict__ c0,     // [512*512] f32
    char* __restrict__ hbase,         // 2 x 512KB buffers
    int* __restrict__ flags,          // [16*32]
    float* __restrict__ out)          // [512][1024]
{
    __shared__ __align__(16) bf16 Alds[32 * 512];  // XOR-swizzled h tile (32 KB)
    __shared__ float xls[32];                      // step-0 correction per row
    __shared__ float WfcLDS[512];
    __shared__ bf16 hrep[32][40];                  // h repack for coalesced stores

    const int tid  = threadIdx.x;
    const int wave = tid >> 6;
    const int lane = tid & 63;
    const int l15  = lane & 15;
    const int hi   = lane >> 4;
    const int xcd = blockIdx.x & 7;
    const int ii  = blockIdx.x >> 3;
    const int bt  = xcd * 2 + (ii & 1);       // 0..15
    const int hs  = ii >> 1;                  // 0..15

    WfcLDS[tid] = Wfc[tid];
    WfcLDS[tid + 256] = Wfc[tid + 256];

    bf16x8 breg[2][16];
    float biasr[2], wihr[2];
    #pragma unroll
    for (int nt = 0; nt < 2; ++nt) {
        int gcol = (nt * 2 + (l15 >> 3)) * HH + hs * 32 + wave * 8 + (l15 & 7);
        const bf16* wp = WcT + (size_t)gcol * HH + hi * 8;
        #pragma unroll
        for (int kk = 0; kk < 16; ++kk)
            breg[nt][kk] = *(const bf16x8*)(wp + kk * 32);
        biasr[nt] = biasC[gcol];
        wihr[nt]  = Wih[gcol];
    }
    const bool lo = (l15 < 8);
    float p0 = __shfl_xor(biasr[0], 8), p1 = __shfl_xor(biasr[1], 8);
    const float bI = lo ? biasr[0] : p0, bF = lo ? p0 : biasr[0];
    const float bG = lo ? biasr[1] : p1, bO = lo ? p1 : biasr[1];
    p0 = __shfl_xor(wihr[0], 8); p1 = __shfl_xor(wihr[1], 8);
    const float wI = lo ? wihr[0] : p0, wF = lo ? p0 : wihr[0];
    const float wG = lo ? wihr[1] : p1, wO = lo ? p1 : wihr[1];

    const int mymt = lo ? 0 : 1;
    const int jcol = wave * 8 + (l15 & 7);
    const int jloc = hs * 32 + jcol;
    float creg[4];
    #pragma unroll
    for (int r = 0; r < 4; ++r) {
        int brow = bt * 32 + mymt * 16 + hi * 4 + r;
        creg[r] = c0[(size_t)brow * HH + jloc];
    }
    const float bfcv = bfc[0];

    const int swz = l15 & 7;
    const int row = tid >> 3;
    const int seg = tid & 7;
    const int r7  = row & 7;

    int* myslots = flags + bt * 32;
    int* myslot  = myslots + hs;

    const size_t grp = ((size_t)(bt * 32 + wave * 8)) * 1024 + (size_t)lane * 16;
    const size_t sto = ((size_t)(bt * 32 + row)) * 1024 + (size_t)hs * 64 + (size_t)seg * 8;
    char* aldsW = (char*)Alds + wave * 8 * 1024;

    __syncthreads();

    for (int s = 0; s <= TT; ++s) {
        if (s == TT && hs != 0) break;

        // 1. detect: 16 lanes poll the group's epoch slots (64B per sweep)
        if (lane < 16) {
            while (__hip_atomic_load(myslots + lane, __ATOMIC_RELAXED,
                                     __HIP_MEMORY_SCOPE_SYSTEM) < s)
                __builtin_amdgcn_s_sleep(1);
        }

        // 2. stage A_s: ONE coalesced sweep (8 x 1KB rows), swizzled LDS
        {
            const char* blo = hbase + (size_t)(s & 1) * BUFSZ + grp;
            const char* bhi = blo + 4096;
            ull2 q0, q1, q2, q3, q4, q5, q6, q7;
            asm volatile(
                "global_load_dwordx4 %0, %8, off sc0 sc1\n\t"
                "global_load_dwordx4 %1, %8, off offset:1024 sc0 sc1\n\t"
                "global_load_dwordx4 %2, %8, off offset:2048 sc0 sc1\n\t"
                "global_load_dwordx4 %3, %8, off offset:3072 sc0 sc1\n\t"
                "global_load_dwordx4 %4, %9, off sc0 sc1\n\t"
                "global_load_dwordx4 %5, %9, off offset:1024 sc0 sc1\n\t"
                "global_load_dwordx4 %6, %9, off offset:2048 sc0 sc1\n\t"
                "global_load_dwordx4 %7, %9, off offset:3072 sc0 sc1\n\t"
                "s_waitcnt vmcnt(0)"
                : "=&v"(q0), "=&v"(q1), "=&v"(q2), "=&v"(q3),
                  "=&v"(q4), "=&v"(q5), "=&v"(q6), "=&v"(q7)
                : "v"(blo), "v"(bhi) : "memory");
            __builtin_amdgcn_sched_barrier(0);
            *(ull2*)(aldsW            + ((lane ^ 0) << 4)) = q0;
            *(ull2*)(aldsW + 1 * 1024 + ((lane ^ 1) << 4)) = q1;
            *(ull2*)(aldsW + 2 * 1024 + ((lane ^ 2) << 4)) = q2;
            *(ull2*)(aldsW + 3 * 1024 + ((lane ^ 3) << 4)) = q3;
            *(ull2*)(aldsW + 4 * 1024 + ((lane ^ 4) << 4)) = q4;
            *(ull2*)(aldsW + 5 * 1024 + ((lane ^ 5) << 4)) = q5;
            *(ull2*)(aldsW + 6 * 1024 + ((lane ^ 6) << 4)) = q6;
            *(ull2*)(aldsW + 7 * 1024 + ((lane ^ 7) << 4)) = q7;
        }
        __syncthreads();

        // LDS granule map: row r, 16B-granule g at r*1024 + ((g ^ (r&7))<<4).
        if (s == 0 || s == TT) {
            float xacc = 0.f;
            const char* arow = (char*)Alds + row * 1024;
            #pragma unroll
            for (int u = 0; u < 8; ++u) {
                int cc = seg * 8 + u;
                bf16x8 v = *(const bf16x8*)(arow + (((cc ^ r7) & 63) << 4));
                const float* wv = WfcLDS + cc * 8;
                #pragma unroll
                for (int e = 0; e < 8; ++e) xacc += (float)v[e] * wv[e];
            }
            xacc += __shfl_xor(xacc, 1);
            xacc += __shfl_xor(xacc, 2);
            xacc += __shfl_xor(xacc, 4);
            xacc += bfcv;
            if (seg == 0) {
                if (s == 0) xls[row] = xacc;
                else out[((size_t)(bt * 32 + row)) * TT + (TT - 1)] = xacc;
            }
            if (s == TT) break;
        }

        // 4. MFMA (granule index (hi + 4*kk) ^ swz)
        f32x4 acc[2][2];
        #pragma unroll
        for (int i = 0; i < 2; ++i)
            #pragma unroll
            for (int j = 0; j < 2; ++j) acc[i][j] = (f32x4)0.f;

        #pragma unroll
        for (int kk = 0; kk < 16; ++kk) {
            int g = (hi + 4 * kk) ^ swz;
            bf16x8 a0 = *(const bf16x8*)((char*)Alds + l15 * 1024 + (g << 4));
            bf16x8 a1 = *(const bf16x8*)((char*)Alds + (l15 + 16) * 1024 + (g << 4));
            acc[0][0] = __builtin_amdgcn_mfma_f32_16x16x32_bf16(a0, breg[0][kk], acc[0][0], 0, 0, 0);
            acc[0][1] = __builtin_amdgcn_mfma_f32_16x16x32_bf16(a0, breg[1][kk], acc[0][1], 0, 0, 0);
            acc[1][0] = __builtin_amdgcn_mfma_f32_16x16x32_bf16(a1, breg[0][kk], acc[1][0], 0, 0, 0);
            acc[1][1] = __builtin_amdgcn_mfma_f32_16x16x32_bf16(a1, breg[1][kk], acc[1][1], 0, 0, 0);
        }

        if (s == 0) __syncthreads();

        // 5. pointwise
        #pragma unroll
        for (int r = 0; r < 4; ++r) {
            float send0 = lo ? acc[1][0][r] : acc[0][0][r];
            float send1 = lo ? acc[1][1][r] : acc[0][1][r];
            float recv0 = __shfl_xor(send0, 8);
            float recv1 = __shfl_xor(send1, 8);
            float own0  = lo ? acc[0][0][r] : acc[1][0][r];
            float own1  = lo ? acc[0][1][r] : acc[1][1][r];
            int  lrow = mymt * 16 + hi * 4 + r;
            float xc = (s == 0) ? xls[lrow] : 0.f;
            float xi = (lo ? own0 : recv0) + bI - xc * wI;
            float xf = (lo ? recv0 : own0) + bF - xc * wF;
            float xg = (lo ? own1 : recv1) + bG - xc * wG;
            float xo = (lo ? recv1 : own1) + bO - xc * wO;
            float si = sigmoid_fast(xi), sf = sigmoid_fast(xf), so = sigmoid_fast(xo);
            float tg = tanh_fast(xg);
            float cn = sf * creg[r] + si * tg;
            creg[r] = cn;
            hrep[lrow][jcol] = (bf16)(so * tanh_fast(cn));
        }
        __syncthreads();

        // 6. store A_{s+1} into buf[(s+1)&1]
        {
            ull val = *(const ull*)&hrep[row][seg * 4];
            char* stp = hbase + (size_t)((s + 1) & 1) * BUFSZ + sto;
            asm volatile("global_store_dwordx2 %0, %1, off sc0 sc1"
                         :: "v"(stp), "v"(val) : "memory");
        }
        __syncthreads();   // per-thread vmcnt(0) drain: all stores at MALL

        // 7. publish epoch
        if (tid == 0)
            __hip_atomic_store(myslot, s + 1, __ATOMIC_RELAXED,
                               __HIP_MEMORY_SCOPE_SYSTEM);

        // 8. round-robin y FC (off critical path)
        if (s > 0 && (s & 15) == hs) {
            float xacc = 0.f;
            const char* arow = (char*)Alds + row * 1024;
            #pragma unroll
            for (int u = 0; u < 8; ++u) {
                int cc = seg * 8 + u;
                bf16x8 v = *(const bf16x8*)(arow + (((cc ^ r7) & 63) << 4));
                const float* wv = WfcLDS + cc * 8;
                #pragma unroll
                for (int e = 0; e < 8; ++e) xacc += (float)v[e] * wv[e];
            }
            xacc += __shfl_xor(xacc, 1);
            xacc += __shfl_xor(xacc, 2);
            xacc += __shfl_xor(xacc, 4);
            if (seg == 0)
                out[((size_t)(bt * 32 + row)) * TT + (s - 1)] = xacc + bfcv;
        }
    }
}

extern "C" void kernel_launch(void* const* d_in, const int* in_sizes, int n_in,
                              void* d_out, int out_size, void* d_ws, size_t ws_size,
                              hipStream_t stream) {
    const float* h   = (const float*)d_in[0];
    const float* c   = (const float*)d_in[1];
    const float* Wih = (const float*)d_in[2];
    const float* Whh = (const float*)d_in[3];
    const float* bih = (const float*)d_in[4];
    const float* bhh = (const float*)d_in[5];
    const float* Wfc = (const float*)d_in[6];
    const float* bfc = (const float*)d_in[7];
    float* out = (float*)d_out;

    char* ws = (char*)d_ws;
    bf16*  WcT   = (bf16*)(ws + WT_OFF);
    float* biasC = (float*)(ws + BC_OFF);
    char*  hb    = ws + H0_OFF;
    int*   flags = (int*)(ws + FL_OFF);

    prep_weights<<<2048, 256, 0, stream>>>(Whh, Wih, bih, bhh, Wfc, bfc, WcT, biasC);
    prep_state<<<1024, 256, 0, stream>>>(h, (bf16*)hb, flags);
    lstm_persist<<<256, 256, 0, stream>>>(WcT, biasC, Wih, Wfc, bfc, c, hb, flags, out);
}